// Round 6
// baseline (49.214 us; speedup 1.0000x reference)
//
#include <hip/hip_runtime.h>
#include <math.h>

#define kNB 16
#define kNA 5
#define kNH 128
#define kNW 128
#define kMaxT 50
#define kNC 20
#define kCH 26
#define kRowW 33
#define kNTot (kNB*kNA*kNH*kNW)         // 1,310,720 cells
#define DENSE_BLOCKS 1280
#define kTS (DENSE_BLOCKS * 256)        // 327,680 threads; 4 cells each, exact
#define SP_BASE (2 * DENSE_BLOCKS)      // sparse partials start (doubles)
#define SP_N 11                         // partials per sparse block

// ws layout (doubles) — every slot written unconditionally every call (no memset):
// [0..1279]            per-block dense softplus partials
// [1280..2559]         per-block dense proposal-count partials
// [2560..2560+16*11)   per-batch sparse partials:
//   j: 0 S_excl 1 cnt_excl 2 nM 3 bce 4 sx 5 sy 6 sw 7 sh 8 ce 9 nGT 10 nCorrect

__device__ __forceinline__ float softplus_fast(float x) {
    return fmaxf(x, 0.0f) + __logf(1.0f + __expf(-fabsf(x)));
}
__device__ __forceinline__ float softplusf(float x) {   // precise, for sparse terms
    return fmaxf(x, 0.0f) + log1pf(expf(-fabsf(x)));
}

__device__ __forceinline__ double wave_sum(double v) {
    #pragma unroll
    for (int off = 32; off > 0; off >>= 1) v += __shfl_down(v, off, 64);
    return v;
}

__device__ __forceinline__ float inv_tanhf(float y) {
    float yc = fminf(fmaxf(y, -1.0f + 1e-6f), 1.0f - 1e-6f);
    float v = 0.5f * logf((1.0f + yc) / (1.0f - yc));
    return (y <= -1.0f) ? -2.0f : ((y >= 1.0f) ? 2.0f : v);
}

extern "C" __global__ __launch_bounds__(256)
void yolo_main(const float* __restrict__ pred, const float* __restrict__ target,
               const int* __restrict__ tsizes, const float* __restrict__ anchors,
               double* __restrict__ ws)
{
    const int tid = threadIdx.x;

    if (blockIdx.x >= kNB) {
        // ====== dense conf gather: ONE float4 per cell (conf at .x or .z) ======
        // conf byte addr = 104*c; float4 idx = (13*c)>>1; parity(c) picks .x / .z.
        // Thread t handles cells c = t, t+kTS, t+2*kTS, t+3*kTS (kTS even -> same parity).
        __shared__ double s_red[8];
        const int bid = (int)blockIdx.x - kNB;          // 0..1279
        const float4* __restrict__ p4 = (const float4*)pred;
        const int t0 = bid * 256 + tid;                 // cell id base, < kTS
        const bool odd = (t0 & 1);

        // 4 independent gathers batched before any use
        float4 v0 = p4[(13 * (t0 + 0 * kTS)) >> 1];
        float4 v1 = p4[(13 * (t0 + 1 * kTS)) >> 1];
        float4 v2 = p4[(13 * (t0 + 2 * kTS)) >> 1];
        float4 v3 = p4[(13 * (t0 + 3 * kTS)) >> 1];

        float p0 = odd ? v0.z : v0.x;
        float p1 = odd ? v1.z : v1.x;
        float p2 = odd ? v2.z : v2.x;
        float p3 = odd ? v3.z : v3.x;

        float sp = softplus_fast(p0) + softplus_fast(p1)
                 + softplus_fast(p2) + softplus_fast(p3);
        int prop = (p0 > 0.0f) + (p1 > 0.0f) + (p2 > 0.0f) + (p3 > 0.0f);

        double spd = wave_sum((double)sp);
        double prd = wave_sum((double)prop);
        int wid = tid >> 6;
        if ((tid & 63) == 0) { s_red[wid] = spd; s_red[4 + wid] = prd; }
        __syncthreads();
        if (tid == 0) {
            ws[bid]                = s_red[0] + s_red[1] + s_red[2] + s_red[3];
            ws[DENSE_BLOCKS + bid] = s_red[4] + s_red[5] + s_red[6] + s_red[7];
        }
        return;
    }

    // ================= sparse targets part (one block per batch) =================
    const int b = blockIdx.x;
    __shared__ float s_t[kMaxT][kRowW];
    __shared__ float s_aw[kNA], s_ah[kNA];
    __shared__ int s_cell[kMaxT], s_bn[kMaxT], s_zm[kMaxT], s_valid[kMaxT];
    __shared__ int s_label[kMaxT];
    __shared__ float s_tx[kMaxT], s_ty[kMaxT], s_tw[kMaxT], s_th[kMaxT];

    for (int i = tid; i < kMaxT * kRowW; i += 256)
        ((float*)s_t)[i] = target[(long long)b * kMaxT * kRowW + i];
    if (tid < kNA) {
        s_aw[tid] = anchors[tid * 2 + 0] / 8.0f;
        s_ah[tid] = anchors[tid * 2 + 1] / 8.0f;
    }
    __syncthreads();

    const int tsz = tsizes[b];
    double ngt = 0.0, ncorr = 0.0;
    int myCell = -1;

    if (tid < kMaxT) {
        const float* row = s_t[tid];
        float gx = row[0] / 8.0f, gy = row[1] / 8.0f;
        float gh = row[3] / 8.0f, gw = row[4] / 8.0f;
        int valid = (tid < tsz) && (gw != 0.0f) && (gh != 0.0f);
        int gi = min(max((int)gx, 0), kNW - 1);
        int gj = min(max((int)gy, 0), kNH - 1);

        float best = -1.0f; int bn = 0; int zm = 0;
        #pragma unroll
        for (int a = 0; a < kNA; ++a) {
            float aw = s_aw[a], ah = s_ah[a];
            float inter = fmaxf(fminf(gw, aw) + 1.0f, 0.0f) * fmaxf(fminf(gh, ah) + 1.0f, 0.0f);
            float iou = inter / ((gw + 1.0f) * (gh + 1.0f) + (aw + 1.0f) * (ah + 1.0f) - inter + 1e-16f);
            if (iou > best) { best = iou; bn = a; }
            if (iou > 0.5f) zm |= (1 << a);
        }

        int lab = 0; float lbest = row[13];
        #pragma unroll
        for (int c = 1; c < kNC; ++c)
            if (row[13 + c] > lbest) { lbest = row[13 + c]; lab = c; }

        long long base = ((((long long)b * kNA + bn) * kNH + gj) * kNW + gi) * kCH;
        float pc = pred[base + 0];
        float px = tanhf(pred[base + 1]) + 0.5f + (float)gi;
        float py = tanhf(pred[base + 2]) + 0.5f + (float)gj;
        float ph = expf(pred[base + 4]) * s_ah[bn];
        float pw = expf(pred[base + 5]) * s_aw[bn];
        float b1x1 = gx - gw, b1x2 = gx + gw, b1y1 = gy - gh, b1y2 = gy + gh;
        float b2x1 = px - pw, b2x2 = px + pw, b2y1 = py - ph, b2y2 = py + ph;
        float iw = fmaxf(fminf(b1x2, b2x2) - fmaxf(b1x1, b2x1) + 1.0f, 0.0f);
        float ih = fmaxf(fminf(b1y2, b2y2) - fmaxf(b1y1, b2y1) + 1.0f, 0.0f);
        float inter2 = iw * ih;
        float a1 = (b1x2 - b1x1 + 1.0f) * (b1y2 - b1y1 + 1.0f);
        float a2 = (b2x2 - b2x1 + 1.0f) * (b2y2 - b2y1 + 1.0f);
        float iou2 = inter2 / (a1 + a2 - inter2 + 1e-16f);
        int plab = 0; float pbest = pred[base + 6];
        #pragma unroll
        for (int c = 1; c < kNC; ++c) {
            float v = pred[base + 6 + c];
            if (v > pbest) { pbest = v; plab = c; }
        }
        int correct = valid && (iou2 > 0.5f) && (plab == lab) && (pc > 0.0f);

        myCell = gj * kNW + gi;
        s_cell[tid] = myCell; s_bn[tid] = bn; s_zm[tid] = zm; s_valid[tid] = valid;
        s_label[tid] = lab;
        s_tx[tid] = inv_tanhf(gx - ((float)gi + 0.5f));
        s_ty[tid] = inv_tanhf(gy - ((float)gj + 0.5f));
        s_tw[tid] = logf(gw / s_aw[bn] + 1e-16f);
        s_th[tid] = logf(gh / s_ah[bn] + 1e-16f);
        ngt = (double)valid; ncorr = (double)correct;
    }
    __syncthreads();

    // lane-parallel last-writer-wins resolution
    double S_excl = 0, cnt_excl = 0, nM = 0, bce = 0;
    double sx = 0, sy = 0, sw_ = 0, sh_ = 0, ce = 0;

    if (tid < kMaxT) {
        int lastTouch[kNA], lastSet[kNA], lastCm[kNA];
        #pragma unroll
        for (int a = 0; a < kNA; ++a) { lastTouch[a] = -1; lastSet[a] = -1; lastCm[a] = 0; }

        for (int tp = 0; tp < kMaxT; ++tp) {
            if (!s_valid[tp] || s_cell[tp] != myCell) continue;
            int bnp = s_bn[tp], zmp = s_zm[tp];
            #pragma unroll
            for (int a = 0; a < kNA; ++a) {
                bool setr = (bnp == a);
                if (setr || ((zmp >> a) & 1)) { lastTouch[a] = tp; lastCm[a] = setr ? 1 : 0; }
                if (setr) lastSet[a] = tp;
            }
        }

        int gj = myCell >> 7, gi = myCell & 127;
        #pragma unroll
        for (int a = 0; a < kNA; ++a) {
            if (lastTouch[a] != tid) continue;          // unique owner per (cell,a)
            bool msk = lastSet[a] >= 0;
            bool cmf = lastCm[a] != 0;
            if (!msk && cmf) continue;
            long long base = ((((long long)b * kNA + a) * kNH + gj) * kNW + gi) * kCH;
            float pc = pred[base];
            float sp2 = softplusf(pc);
            S_excl += (double)sp2; cnt_excl += 1.0;
            if (msk) {
                int ts = lastSet[a];
                nM += 1.0; bce += (double)(sp2 - pc);
                float dx = pred[base + 1] - s_tx[ts];
                float dy = pred[base + 2] - s_ty[ts];
                float dh = pred[base + 4] - s_th[ts];
                float dw = pred[base + 5] - s_tw[ts];
                sx += (double)(dx * dx); sy += (double)(dy * dy);
                sw_ += (double)(dw * dw); sh_ += (double)(dh * dh);
                float m20 = pred[base + 6];
                #pragma unroll
                for (int c = 1; c < kNC; ++c) m20 = fmaxf(m20, pred[base + 6 + c]);
                float es = 0.0f;
                #pragma unroll
                for (int c = 0; c < kNC; ++c) es += expf(pred[base + 6 + c] - m20);
                ce += (double)(m20 + logf(es) - pred[base + 6 + s_label[ts]]);
            }
        }
    }

    if (tid < 64) {
        S_excl = wave_sum(S_excl); cnt_excl = wave_sum(cnt_excl);
        nM = wave_sum(nM); bce = wave_sum(bce);
        sx = wave_sum(sx); sy = wave_sum(sy); sw_ = wave_sum(sw_); sh_ = wave_sum(sh_);
        ce = wave_sum(ce); ngt = wave_sum(ngt); ncorr = wave_sum(ncorr);
        if (tid == 0) {
            double* o = &ws[SP_BASE + b * SP_N];
            o[0] = S_excl; o[1] = cnt_excl; o[2] = nM; o[3] = bce;
            o[4] = sx; o[5] = sy; o[6] = sw_; o[7] = sh_;
            o[8] = ce; o[9] = ngt; o[10] = ncorr;
        }
    }
}

extern "C" __global__ __launch_bounds__(256)
void yolo_finalize(const double* __restrict__ ws, float* __restrict__ out) {
    __shared__ double s_red[8];
    __shared__ double s_sp[kNB * SP_N];
    __shared__ double s_acc[SP_N];
    const int tid = threadIdx.x;

    if (tid < kNB * SP_N) s_sp[tid] = ws[SP_BASE + tid];

    double sp = 0.0, pr = 0.0;
    for (int i = tid; i < DENSE_BLOCKS; i += 256) {
        sp += ws[i];
        pr += ws[DENSE_BLOCKS + i];
    }
    sp = wave_sum(sp); pr = wave_sum(pr);
    int wid = tid >> 6;
    if ((tid & 63) == 0) { s_red[wid] = sp; s_red[4 + wid] = pr; }
    __syncthreads();

    if (tid < SP_N) {
        double acc = 0.0;
        #pragma unroll
        for (int b = 0; b < kNB; ++b) acc += s_sp[b * SP_N + tid];
        s_acc[tid] = acc;
    }
    __syncthreads();

    if (tid == 0) {
        double S_all = s_red[0] + s_red[1] + s_red[2] + s_red[3];
        double nProp = s_red[4] + s_red[5] + s_red[6] + s_red[7];
        double S_excl = s_acc[0], cnt_excl = s_acc[1];
        double nMc = s_acc[2], bce = s_acc[3];
        double sx = s_acc[4], sy = s_acc[5], sw = s_acc[6], sh = s_acc[7];
        double ce = s_acc[8], nGT = s_acc[9], nCorr = s_acc[10];
        double nM = fmax(nMc, 1.0);
        double nF = fmax((double)kNTot - cnt_excl, 1.0);
        double loss_conf = 1.25 * (S_all - S_excl) / nF + bce / nM;
        double loss = (sx + sy + sw + sh) / nM + loss_conf + (ce / nM) / 16.0;
        double recall = (nGT > 0.0) ? nCorr / fmax(nGT, 1.0) : 1.0;
        double precision = (nProp > 0.0) ? nCorr / fmax(nProp, 1.0) : 1.0;
        out[0] = (float)loss;
        out[1] = (float)recall;
        out[2] = (float)precision;
    }
}

extern "C" void kernel_launch(void* const* d_in, const int* in_sizes, int n_in,
                              void* d_out, int out_size, void* d_ws, size_t ws_size,
                              hipStream_t stream) {
    const float* pred    = (const float*)d_in[0];
    const float* target  = (const float*)d_in[1];
    const int*   tsizes  = (const int*)d_in[2];
    const float* anchors = (const float*)d_in[3];
    float* out = (float*)d_out;
    double* ws = (double*)d_ws;

    yolo_main<<<DENSE_BLOCKS + kNB, 256, 0, stream>>>(pred, target, tsizes, anchors, ws);
    yolo_finalize<<<1, 256, 0, stream>>>(ws, out);
}

// Round 7
// 45.111 us; speedup vs baseline: 1.0909x; 1.0909x over previous
//
#include <hip/hip_runtime.h>
#include <math.h>

#define kNB 16
#define kNA 5
#define kNH 128
#define kNW 128
#define kMaxT 50
#define kNC 20
#define kCH 26
#define kRowW 33
#define kNTot (kNB*kNA*kNH*kNW)         // 1,310,720 cells
#define DENSE_BLOCKS 2048
#define TILE_F4 4160                    // float4s per dense block; 2048*4160 = 8,519,680 exact
#define SP_BASE (2 * DENSE_BLOCKS)      // sparse partials start (doubles)
#define SP_N 11                         // partials per sparse block

// ws layout (doubles) — every slot written unconditionally every call (no memset):
// [0..2047]            per-block dense softplus partials
// [2048..4095]         per-block dense proposal-count partials
// [4096..4096+16*11)   per-batch sparse partials:
//   j: 0 S_excl 1 cnt_excl 2 nM 3 bce 4 sx 5 sy 6 sw 7 sh 8 ce 9 nGT 10 nCorrect

__device__ __forceinline__ float softplus_fast(float x) {
    return fmaxf(x, 0.0f) + __logf(1.0f + __expf(-fabsf(x)));
}
__device__ __forceinline__ float softplusf(float x) {   // precise, for sparse terms
    return fmaxf(x, 0.0f) + log1pf(expf(-fabsf(x)));
}

__device__ __forceinline__ double wave_sum(double v) {
    #pragma unroll
    for (int off = 32; off > 0; off >>= 1) v += __shfl_down(v, off, 64);
    return v;
}

__device__ __forceinline__ float inv_tanhf(float y) {
    float yc = fminf(fmaxf(y, -1.0f + 1e-6f), 1.0f - 1e-6f);
    float v = 0.5f * logf((1.0f + yc) / (1.0f - yc));
    return (y <= -1.0f) ? -2.0f : ((y >= 1.0f) ? 2.0f : v);
}

// r = (4*float4_index) % 26 is always EVEN -> conf present iff r==0 (.x) or r==24 (.z)
__device__ __forceinline__ void conf_step(const float4 v, int r, float& sp, int& prop) {
    bool is0 = (r == 0);
    bool has = is0 | (r == 24);
    float p = is0 ? v.x : v.z;
    float s = softplus_fast(p);
    sp += has ? s : 0.0f;
    prop += (has & (p > 0.0f)) ? 1 : 0;
}

extern "C" __global__ __launch_bounds__(256)
void yolo_main(const float* __restrict__ pred, const float* __restrict__ target,
               const int* __restrict__ tsizes, const float* __restrict__ anchors,
               double* __restrict__ ws)
{
    const int tid = threadIdx.x;

    if (blockIdx.x >= kNB) {
        // ===== dense conf stream: block-contiguous 65KB tiles, XCD-swizzled =====
        // tile stride 4160 f4 = 16640 dwords ≡ 0 (mod 26) -> residues depend on (tid,k) only.
        __shared__ double s_red[8];
        const int bid = (int)blockIdx.x - kNB;            // 0..2047
        // XCD-aware swizzle: XCD (bid&7) gets contiguous tiles [256*(bid&7), +256)
        const int tile = (bid & 7) * (DENSE_BLOCKS / 8) + (bid >> 3);
        const float4* __restrict__ p4 = (const float4*)pred;
        const int base = tile * TILE_F4 + tid;            // f4 index
        int rb = (4 * tid) % 26;                          // even

        // (1024*k) % 26 for k=0..16
        constexpr int OFF[17] = {0,10,20,4,14,24,8,18,2,12,22,6,16,0,10,20,4};

        float sp = 0.0f;
        int prop = 0;

        #pragma unroll
        for (int g = 0; g < 2; ++g) {
            float4 v[8];
            #pragma unroll
            for (int j = 0; j < 8; ++j) v[j] = p4[base + (8 * g + j) * 256];
            #pragma unroll
            for (int j = 0; j < 8; ++j) {
                int rk = rb + OFF[8 * g + j];
                rk = (rk >= 26) ? rk - 26 : rk;
                conf_step(v[j], rk, sp, prop);
            }
        }
        if (tid < TILE_F4 - 16 * 256) {                   // 64-thread tail, k=16
            int rk = rb + OFF[16];
            rk = (rk >= 26) ? rk - 26 : rk;
            conf_step(p4[base + 16 * 256], rk, sp, prop);
        }

        double spd = wave_sum((double)sp);
        double prd = wave_sum((double)prop);
        int wid = tid >> 6;
        if ((tid & 63) == 0) { s_red[wid] = spd; s_red[4 + wid] = prd; }
        __syncthreads();
        if (tid == 0) {
            ws[bid]                = s_red[0] + s_red[1] + s_red[2] + s_red[3];
            ws[DENSE_BLOCKS + bid] = s_red[4] + s_red[5] + s_red[6] + s_red[7];
        }
        return;
    }

    // ================= sparse targets part (one block per batch) =================
    const int b = blockIdx.x;
    __shared__ float s_t[kMaxT][kRowW];
    __shared__ float s_aw[kNA], s_ah[kNA];
    __shared__ int s_cell[kMaxT], s_bn[kMaxT], s_zm[kMaxT], s_valid[kMaxT];
    __shared__ int s_label[kMaxT];
    __shared__ float s_tx[kMaxT], s_ty[kMaxT], s_tw[kMaxT], s_th[kMaxT];

    for (int i = tid; i < kMaxT * kRowW; i += 256)
        ((float*)s_t)[i] = target[(long long)b * kMaxT * kRowW + i];
    if (tid < kNA) {
        s_aw[tid] = anchors[tid * 2 + 0] / 8.0f;
        s_ah[tid] = anchors[tid * 2 + 1] / 8.0f;
    }
    __syncthreads();

    const int tsz = tsizes[b];
    double ngt = 0.0, ncorr = 0.0;
    int myCell = -1;

    if (tid < kMaxT) {
        const float* row = s_t[tid];
        float gx = row[0] / 8.0f, gy = row[1] / 8.0f;
        float gh = row[3] / 8.0f, gw = row[4] / 8.0f;
        int valid = (tid < tsz) && (gw != 0.0f) && (gh != 0.0f);
        int gi = min(max((int)gx, 0), kNW - 1);
        int gj = min(max((int)gy, 0), kNH - 1);

        float best = -1.0f; int bn = 0; int zm = 0;
        #pragma unroll
        for (int a = 0; a < kNA; ++a) {
            float aw = s_aw[a], ah = s_ah[a];
            float inter = fmaxf(fminf(gw, aw) + 1.0f, 0.0f) * fmaxf(fminf(gh, ah) + 1.0f, 0.0f);
            float iou = inter / ((gw + 1.0f) * (gh + 1.0f) + (aw + 1.0f) * (ah + 1.0f) - inter + 1e-16f);
            if (iou > best) { best = iou; bn = a; }
            if (iou > 0.5f) zm |= (1 << a);
        }

        int lab = 0; float lbest = row[13];
        #pragma unroll
        for (int c = 1; c < kNC; ++c)
            if (row[13 + c] > lbest) { lbest = row[13 + c]; lab = c; }

        long long base = ((((long long)b * kNA + bn) * kNH + gj) * kNW + gi) * kCH;
        float pc = pred[base + 0];
        float px = tanhf(pred[base + 1]) + 0.5f + (float)gi;
        float py = tanhf(pred[base + 2]) + 0.5f + (float)gj;
        float ph = expf(pred[base + 4]) * s_ah[bn];
        float pw = expf(pred[base + 5]) * s_aw[bn];
        float b1x1 = gx - gw, b1x2 = gx + gw, b1y1 = gy - gh, b1y2 = gy + gh;
        float b2x1 = px - pw, b2x2 = px + pw, b2y1 = py - ph, b2y2 = py + ph;
        float iw = fmaxf(fminf(b1x2, b2x2) - fmaxf(b1x1, b2x1) + 1.0f, 0.0f);
        float ih = fmaxf(fminf(b1y2, b2y2) - fmaxf(b1y1, b2y1) + 1.0f, 0.0f);
        float inter2 = iw * ih;
        float a1 = (b1x2 - b1x1 + 1.0f) * (b1y2 - b1y1 + 1.0f);
        float a2 = (b2x2 - b2x1 + 1.0f) * (b2y2 - b2y1 + 1.0f);
        float iou2 = inter2 / (a1 + a2 - inter2 + 1e-16f);
        int plab = 0; float pbest = pred[base + 6];
        #pragma unroll
        for (int c = 1; c < kNC; ++c) {
            float v = pred[base + 6 + c];
            if (v > pbest) { pbest = v; plab = c; }
        }
        int correct = valid && (iou2 > 0.5f) && (plab == lab) && (pc > 0.0f);

        myCell = gj * kNW + gi;
        s_cell[tid] = myCell; s_bn[tid] = bn; s_zm[tid] = zm; s_valid[tid] = valid;
        s_label[tid] = lab;
        s_tx[tid] = inv_tanhf(gx - ((float)gi + 0.5f));
        s_ty[tid] = inv_tanhf(gy - ((float)gj + 0.5f));
        s_tw[tid] = logf(gw / s_aw[bn] + 1e-16f);
        s_th[tid] = logf(gh / s_ah[bn] + 1e-16f);
        ngt = (double)valid; ncorr = (double)correct;
    }
    __syncthreads();

    // lane-parallel last-writer-wins resolution
    double S_excl = 0, cnt_excl = 0, nM = 0, bce = 0;
    double sx = 0, sy = 0, sw_ = 0, sh_ = 0, ce = 0;

    if (tid < kMaxT) {
        int lastTouch[kNA], lastSet[kNA], lastCm[kNA];
        #pragma unroll
        for (int a = 0; a < kNA; ++a) { lastTouch[a] = -1; lastSet[a] = -1; lastCm[a] = 0; }

        for (int tp = 0; tp < kMaxT; ++tp) {
            if (!s_valid[tp] || s_cell[tp] != myCell) continue;
            int bnp = s_bn[tp], zmp = s_zm[tp];
            #pragma unroll
            for (int a = 0; a < kNA; ++a) {
                bool setr = (bnp == a);
                if (setr || ((zmp >> a) & 1)) { lastTouch[a] = tp; lastCm[a] = setr ? 1 : 0; }
                if (setr) lastSet[a] = tp;
            }
        }

        int gj = myCell >> 7, gi = myCell & 127;
        #pragma unroll
        for (int a = 0; a < kNA; ++a) {
            if (lastTouch[a] != tid) continue;          // unique owner per (cell,a)
            bool msk = lastSet[a] >= 0;
            bool cmf = lastCm[a] != 0;
            if (!msk && cmf) continue;
            long long base = ((((long long)b * kNA + a) * kNH + gj) * kNW + gi) * kCH;
            float pc = pred[base];
            float sp2 = softplusf(pc);
            S_excl += (double)sp2; cnt_excl += 1.0;
            if (msk) {
                int ts = lastSet[a];
                nM += 1.0; bce += (double)(sp2 - pc);
                float dx = pred[base + 1] - s_tx[ts];
                float dy = pred[base + 2] - s_ty[ts];
                float dh = pred[base + 4] - s_th[ts];
                float dw = pred[base + 5] - s_tw[ts];
                sx += (double)(dx * dx); sy += (double)(dy * dy);
                sw_ += (double)(dw * dw); sh_ += (double)(dh * dh);
                float m20 = pred[base + 6];
                #pragma unroll
                for (int c = 1; c < kNC; ++c) m20 = fmaxf(m20, pred[base + 6 + c]);
                float es = 0.0f;
                #pragma unroll
                for (int c = 0; c < kNC; ++c) es += expf(pred[base + 6 + c] - m20);
                ce += (double)(m20 + logf(es) - pred[base + 6 + s_label[ts]]);
            }
        }
    }

    if (tid < 64) {
        S_excl = wave_sum(S_excl); cnt_excl = wave_sum(cnt_excl);
        nM = wave_sum(nM); bce = wave_sum(bce);
        sx = wave_sum(sx); sy = wave_sum(sy); sw_ = wave_sum(sw_); sh_ = wave_sum(sh_);
        ce = wave_sum(ce); ngt = wave_sum(ngt); ncorr = wave_sum(ncorr);
        if (tid == 0) {
            double* o = &ws[SP_BASE + b * SP_N];
            o[0] = S_excl; o[1] = cnt_excl; o[2] = nM; o[3] = bce;
            o[4] = sx; o[5] = sy; o[6] = sw_; o[7] = sh_;
            o[8] = ce; o[9] = ngt; o[10] = ncorr;
        }
    }
}

extern "C" __global__ __launch_bounds__(256)
void yolo_finalize(const double* __restrict__ ws, float* __restrict__ out) {
    __shared__ double s_red[8];
    __shared__ double s_sp[kNB * SP_N];
    __shared__ double s_acc[SP_N];
    const int tid = threadIdx.x;

    if (tid < kNB * SP_N) s_sp[tid] = ws[SP_BASE + tid];

    double sp = 0.0, pr = 0.0;
    for (int i = tid; i < DENSE_BLOCKS; i += 256) {
        sp += ws[i];
        pr += ws[DENSE_BLOCKS + i];
    }
    sp = wave_sum(sp); pr = wave_sum(pr);
    int wid = tid >> 6;
    if ((tid & 63) == 0) { s_red[wid] = sp; s_red[4 + wid] = pr; }
    __syncthreads();

    if (tid < SP_N) {
        double acc = 0.0;
        #pragma unroll
        for (int b = 0; b < kNB; ++b) acc += s_sp[b * SP_N + tid];
        s_acc[tid] = acc;
    }
    __syncthreads();

    if (tid == 0) {
        double S_all = s_red[0] + s_red[1] + s_red[2] + s_red[3];
        double nProp = s_red[4] + s_red[5] + s_red[6] + s_red[7];
        double S_excl = s_acc[0], cnt_excl = s_acc[1];
        double nMc = s_acc[2], bce = s_acc[3];
        double sx = s_acc[4], sy = s_acc[5], sw = s_acc[6], sh = s_acc[7];
        double ce = s_acc[8], nGT = s_acc[9], nCorr = s_acc[10];
        double nM = fmax(nMc, 1.0);
        double nF = fmax((double)kNTot - cnt_excl, 1.0);
        double loss_conf = 1.25 * (S_all - S_excl) / nF + bce / nM;
        double loss = (sx + sy + sw + sh) / nM + loss_conf + (ce / nM) / 16.0;
        double recall = (nGT > 0.0) ? nCorr / fmax(nGT, 1.0) : 1.0;
        double precision = (nProp > 0.0) ? nCorr / fmax(nProp, 1.0) : 1.0;
        out[0] = (float)loss;
        out[1] = (float)recall;
        out[2] = (float)precision;
    }
}

extern "C" void kernel_launch(void* const* d_in, const int* in_sizes, int n_in,
                              void* d_out, int out_size, void* d_ws, size_t ws_size,
                              hipStream_t stream) {
    const float* pred    = (const float*)d_in[0];
    const float* target  = (const float*)d_in[1];
    const int*   tsizes  = (const int*)d_in[2];
    const float* anchors = (const float*)d_in[3];
    float* out = (float*)d_out;
    double* ws = (double*)d_ws;

    yolo_main<<<DENSE_BLOCKS + kNB, 256, 0, stream>>>(pred, target, tsizes, anchors, ws);
    yolo_finalize<<<1, 256, 0, stream>>>(ws, out);
}

// Round 8
// 39.718 us; speedup vs baseline: 1.2391x; 1.1358x over previous
//
#include <hip/hip_runtime.h>
#include <math.h>

#define kNB 16
#define kNA 5
#define kNH 128
#define kNW 128
#define kMaxT 50
#define kNC 20
#define kCH 26
#define kRowW 33
#define kNTot (kNB*kNA*kNH*kNW)         // 1,310,720 cells
#define DENSE_BLOCKS 2048
#define TILE_F4 4160                    // float4s per dense block; 2048*4160 = 8,519,680 exact
#define SP_BASE (2 * DENSE_BLOCKS)      // sparse partials start (doubles)
#define SP_N 11                         // partials per sparse block

typedef float f4_t __attribute__((ext_vector_type(4)));

// ws layout (doubles) — every slot written unconditionally every call (no memset):
// [0..2047]            per-block dense softplus partials
// [2048..4095]         per-block dense proposal-count partials
// [4096..4096+16*11)   per-batch sparse partials:
//   j: 0 S_excl 1 cnt_excl 2 nM 3 bce 4 sx 5 sy 6 sw 7 sh 8 ce 9 nGT 10 nCorrect

__device__ __forceinline__ float softplus_fast(float x) {
    return fmaxf(x, 0.0f) + __logf(1.0f + __expf(-fabsf(x)));
}
__device__ __forceinline__ float softplusf(float x) {   // precise, for sparse terms
    return fmaxf(x, 0.0f) + log1pf(expf(-fabsf(x)));
}

__device__ __forceinline__ double wave_sum(double v) {
    #pragma unroll
    for (int off = 32; off > 0; off >>= 1) v += __shfl_down(v, off, 64);
    return v;
}

__device__ __forceinline__ float inv_tanhf(float y) {
    float yc = fminf(fmaxf(y, -1.0f + 1e-6f), 1.0f - 1e-6f);
    float v = 0.5f * logf((1.0f + yc) / (1.0f - yc));
    return (y <= -1.0f) ? -2.0f : ((y >= 1.0f) ? 2.0f : v);
}

// r = (4*float4_index) % 26 is always EVEN -> conf present iff r==0 ([0]) or r==24 ([2])
__device__ __forceinline__ void conf_step(const f4_t v, int r, float& sp, int& prop) {
    bool is0 = (r == 0);
    bool has = is0 | (r == 24);
    float p = is0 ? v[0] : v[2];
    float s = softplus_fast(p);
    sp += has ? s : 0.0f;
    prop += (has & (p > 0.0f)) ? 1 : 0;
}

extern "C" __global__ __launch_bounds__(256)
void yolo_main(const float* __restrict__ pred, const float* __restrict__ target,
               const int* __restrict__ tsizes, const float* __restrict__ anchors,
               double* __restrict__ ws)
{
    const int tid = threadIdx.x;

    if (blockIdx.x >= kNB) {
        // ===== dense conf stream: 65KB contiguous tiles, XCD-swizzled, NT loads =====
        __shared__ double s_red[8];
        const int bid = (int)blockIdx.x - kNB;            // 0..2047
        const int tile = (bid & 7) * (DENSE_BLOCKS / 8) + (bid >> 3);
        const f4_t* __restrict__ p4 = (const f4_t*)pred;
        const int base = tile * TILE_F4 + tid;            // f4 index
        int rb = (4 * tid) % 26;                          // even

        // (1024*k) % 26 for k=0..16
        constexpr int OFF[17] = {0,10,20,4,14,24,8,18,2,12,22,6,16,0,10,20,4};

        float sp = 0.0f;
        int prop = 0;

        #pragma unroll
        for (int g = 0; g < 2; ++g) {
            f4_t v[8];
            #pragma unroll
            for (int j = 0; j < 8; ++j)
                v[j] = __builtin_nontemporal_load(&p4[base + (8 * g + j) * 256]);
            #pragma unroll
            for (int j = 0; j < 8; ++j) {
                int rk = rb + OFF[8 * g + j];
                rk = (rk >= 26) ? rk - 26 : rk;
                conf_step(v[j], rk, sp, prop);
            }
        }
        if (tid < TILE_F4 - 16 * 256) {                   // 64-thread tail, k=16
            int rk = rb + OFF[16];
            rk = (rk >= 26) ? rk - 26 : rk;
            f4_t vt = __builtin_nontemporal_load(&p4[base + 16 * 256]);
            conf_step(vt, rk, sp, prop);
        }

        double spd = wave_sum((double)sp);
        double prd = wave_sum((double)prop);
        int wid = tid >> 6;
        if ((tid & 63) == 0) { s_red[wid] = spd; s_red[4 + wid] = prd; }
        __syncthreads();
        if (tid == 0) {
            ws[bid]                = s_red[0] + s_red[1] + s_red[2] + s_red[3];
            ws[DENSE_BLOCKS + bid] = s_red[4] + s_red[5] + s_red[6] + s_red[7];
        }
        return;
    }

    // ================= sparse targets part (one block per batch) =================
    const int b = blockIdx.x;
    __shared__ float s_t[kMaxT][kRowW];
    __shared__ float s_aw[kNA], s_ah[kNA];
    __shared__ int s_cell[kMaxT], s_bn[kMaxT], s_zm[kMaxT], s_valid[kMaxT];
    __shared__ int s_label[kMaxT];
    __shared__ float s_tx[kMaxT], s_ty[kMaxT], s_tw[kMaxT], s_th[kMaxT];

    for (int i = tid; i < kMaxT * kRowW; i += 256)
        ((float*)s_t)[i] = target[(long long)b * kMaxT * kRowW + i];
    if (tid < kNA) {
        s_aw[tid] = anchors[tid * 2 + 0] / 8.0f;
        s_ah[tid] = anchors[tid * 2 + 1] / 8.0f;
    }
    __syncthreads();

    const int tsz = tsizes[b];
    double ngt = 0.0, ncorr = 0.0;
    int myCell = -1;

    if (tid < kMaxT) {
        const float* row = s_t[tid];
        float gx = row[0] / 8.0f, gy = row[1] / 8.0f;
        float gh = row[3] / 8.0f, gw = row[4] / 8.0f;
        int valid = (tid < tsz) && (gw != 0.0f) && (gh != 0.0f);
        int gi = min(max((int)gx, 0), kNW - 1);
        int gj = min(max((int)gy, 0), kNH - 1);

        float best = -1.0f; int bn = 0; int zm = 0;
        #pragma unroll
        for (int a = 0; a < kNA; ++a) {
            float aw = s_aw[a], ah = s_ah[a];
            float inter = fmaxf(fminf(gw, aw) + 1.0f, 0.0f) * fmaxf(fminf(gh, ah) + 1.0f, 0.0f);
            float iou = inter / ((gw + 1.0f) * (gh + 1.0f) + (aw + 1.0f) * (ah + 1.0f) - inter + 1e-16f);
            if (iou > best) { best = iou; bn = a; }
            if (iou > 0.5f) zm |= (1 << a);
        }

        int lab = 0; float lbest = row[13];
        #pragma unroll
        for (int c = 1; c < kNC; ++c)
            if (row[13 + c] > lbest) { lbest = row[13 + c]; lab = c; }

        long long base = ((((long long)b * kNA + bn) * kNH + gj) * kNW + gi) * kCH;
        float pc = pred[base + 0];
        float px = tanhf(pred[base + 1]) + 0.5f + (float)gi;
        float py = tanhf(pred[base + 2]) + 0.5f + (float)gj;
        float ph = expf(pred[base + 4]) * s_ah[bn];
        float pw = expf(pred[base + 5]) * s_aw[bn];
        float b1x1 = gx - gw, b1x2 = gx + gw, b1y1 = gy - gh, b1y2 = gy + gh;
        float b2x1 = px - pw, b2x2 = px + pw, b2y1 = py - ph, b2y2 = py + ph;
        float iw = fmaxf(fminf(b1x2, b2x2) - fmaxf(b1x1, b2x1) + 1.0f, 0.0f);
        float ih = fmaxf(fminf(b1y2, b2y2) - fmaxf(b1y1, b2y1) + 1.0f, 0.0f);
        float inter2 = iw * ih;
        float a1 = (b1x2 - b1x1 + 1.0f) * (b1y2 - b1y1 + 1.0f);
        float a2 = (b2x2 - b2x1 + 1.0f) * (b2y2 - b2y1 + 1.0f);
        float iou2 = inter2 / (a1 + a2 - inter2 + 1e-16f);
        int plab = 0; float pbest = pred[base + 6];
        #pragma unroll
        for (int c = 1; c < kNC; ++c) {
            float v = pred[base + 6 + c];
            if (v > pbest) { pbest = v; plab = c; }
        }
        int correct = valid && (iou2 > 0.5f) && (plab == lab) && (pc > 0.0f);

        myCell = gj * kNW + gi;
        s_cell[tid] = myCell; s_bn[tid] = bn; s_zm[tid] = zm; s_valid[tid] = valid;
        s_label[tid] = lab;
        s_tx[tid] = inv_tanhf(gx - ((float)gi + 0.5f));
        s_ty[tid] = inv_tanhf(gy - ((float)gj + 0.5f));
        s_tw[tid] = logf(gw / s_aw[bn] + 1e-16f);
        s_th[tid] = logf(gh / s_ah[bn] + 1e-16f);
        ngt = (double)valid; ncorr = (double)correct;
    }
    __syncthreads();

    // lane-parallel last-writer-wins resolution
    double S_excl = 0, cnt_excl = 0, nM = 0, bce = 0;
    double sx = 0, sy = 0, sw_ = 0, sh_ = 0, ce = 0;

    if (tid < kMaxT) {
        int lastTouch[kNA], lastSet[kNA], lastCm[kNA];
        #pragma unroll
        for (int a = 0; a < kNA; ++a) { lastTouch[a] = -1; lastSet[a] = -1; lastCm[a] = 0; }

        for (int tp = 0; tp < kMaxT; ++tp) {
            if (!s_valid[tp] || s_cell[tp] != myCell) continue;
            int bnp = s_bn[tp], zmp = s_zm[tp];
            #pragma unroll
            for (int a = 0; a < kNA; ++a) {
                bool setr = (bnp == a);
                if (setr || ((zmp >> a) & 1)) { lastTouch[a] = tp; lastCm[a] = setr ? 1 : 0; }
                if (setr) lastSet[a] = tp;
            }
        }

        int gj = myCell >> 7, gi = myCell & 127;
        #pragma unroll
        for (int a = 0; a < kNA; ++a) {
            if (lastTouch[a] != tid) continue;          // unique owner per (cell,a)
            bool msk = lastSet[a] >= 0;
            bool cmf = lastCm[a] != 0;
            if (!msk && cmf) continue;
            long long base = ((((long long)b * kNA + a) * kNH + gj) * kNW + gi) * kCH;
            float pc = pred[base];
            float sp2 = softplusf(pc);
            S_excl += (double)sp2; cnt_excl += 1.0;
            if (msk) {
                int ts = lastSet[a];
                nM += 1.0; bce += (double)(sp2 - pc);
                float dx = pred[base + 1] - s_tx[ts];
                float dy = pred[base + 2] - s_ty[ts];
                float dh = pred[base + 4] - s_th[ts];
                float dw = pred[base + 5] - s_tw[ts];
                sx += (double)(dx * dx); sy += (double)(dy * dy);
                sw_ += (double)(dw * dw); sh_ += (double)(dh * dh);
                float m20 = pred[base + 6];
                #pragma unroll
                for (int c = 1; c < kNC; ++c) m20 = fmaxf(m20, pred[base + 6 + c]);
                float es = 0.0f;
                #pragma unroll
                for (int c = 0; c < kNC; ++c) es += expf(pred[base + 6 + c] - m20);
                ce += (double)(m20 + logf(es) - pred[base + 6 + s_label[ts]]);
            }
        }
    }

    if (tid < 64) {
        S_excl = wave_sum(S_excl); cnt_excl = wave_sum(cnt_excl);
        nM = wave_sum(nM); bce = wave_sum(bce);
        sx = wave_sum(sx); sy = wave_sum(sy); sw_ = wave_sum(sw_); sh_ = wave_sum(sh_);
        ce = wave_sum(ce); ngt = wave_sum(ngt); ncorr = wave_sum(ncorr);
        if (tid == 0) {
            double* o = &ws[SP_BASE + b * SP_N];
            o[0] = S_excl; o[1] = cnt_excl; o[2] = nM; o[3] = bce;
            o[4] = sx; o[5] = sy; o[6] = sw_; o[7] = sh_;
            o[8] = ce; o[9] = ngt; o[10] = ncorr;
        }
    }
}

extern "C" __global__ __launch_bounds__(256)
void yolo_finalize(const double* __restrict__ ws, float* __restrict__ out) {
    __shared__ double s_red[8];
    __shared__ double s_sp[kNB * SP_N];
    __shared__ double s_acc[SP_N];
    const int tid = threadIdx.x;

    if (tid < kNB * SP_N) s_sp[tid] = ws[SP_BASE + tid];

    double sp = 0.0, pr = 0.0;
    for (int i = tid; i < DENSE_BLOCKS; i += 256) {
        sp += ws[i];
        pr += ws[DENSE_BLOCKS + i];
    }
    sp = wave_sum(sp); pr = wave_sum(pr);
    int wid = tid >> 6;
    if ((tid & 63) == 0) { s_red[wid] = sp; s_red[4 + wid] = pr; }
    __syncthreads();

    if (tid < SP_N) {
        double acc = 0.0;
        #pragma unroll
        for (int b = 0; b < kNB; ++b) acc += s_sp[b * SP_N + tid];
        s_acc[tid] = acc;
    }
    __syncthreads();

    if (tid == 0) {
        double S_all = s_red[0] + s_red[1] + s_red[2] + s_red[3];
        double nProp = s_red[4] + s_red[5] + s_red[6] + s_red[7];
        double S_excl = s_acc[0], cnt_excl = s_acc[1];
        double nMc = s_acc[2], bce = s_acc[3];
        double sx = s_acc[4], sy = s_acc[5], sw = s_acc[6], sh = s_acc[7];
        double ce = s_acc[8], nGT = s_acc[9], nCorr = s_acc[10];
        double nM = fmax(nMc, 1.0);
        double nF = fmax((double)kNTot - cnt_excl, 1.0);
        double loss_conf = 1.25 * (S_all - S_excl) / nF + bce / nM;
        double loss = (sx + sy + sw + sh) / nM + loss_conf + (ce / nM) / 16.0;
        double recall = (nGT > 0.0) ? nCorr / fmax(nGT, 1.0) : 1.0;
        double precision = (nProp > 0.0) ? nCorr / fmax(nProp, 1.0) : 1.0;
        out[0] = (float)loss;
        out[1] = (float)recall;
        out[2] = (float)precision;
    }
}

extern "C" void kernel_launch(void* const* d_in, const int* in_sizes, int n_in,
                              void* d_out, int out_size, void* d_ws, size_t ws_size,
                              hipStream_t stream) {
    const float* pred    = (const float*)d_in[0];
    const float* target  = (const float*)d_in[1];
    const int*   tsizes  = (const int*)d_in[2];
    const float* anchors = (const float*)d_in[3];
    float* out = (float*)d_out;
    double* ws = (double*)d_ws;

    yolo_main<<<DENSE_BLOCKS + kNB, 256, 0, stream>>>(pred, target, tsizes, anchors, ws);
    yolo_finalize<<<1, 256, 0, stream>>>(ws, out);
}